// Round 1
// baseline (20.838 us; speedup 1.0000x reference)
//
#include <hip/hip_runtime.h>

// Problem constants (fixed by the reference).
#define BB   32
#define HH   512
#define WW   512
#define HCC  256
#define WCC  256
#define NPIX (HH * WW)          // 262144 = 2^18
#define NELEM (BB * NPIX)       // 8388608 floats per output tensor

// Output layout: d_out[0 .. NELEM)        = y_initial (copy)
//                d_out[NELEM .. 2*NELEM)  = pasted nearest-resize
__global__ __launch_bounds__(256) void TransformedSegmentation_84971632984244_kernel(
    const float* __restrict__ y_initial,
    const float* __restrict__ y_cropped,
    const int*   __restrict__ bboxes,
    float*       __restrict__ out)
{
    const int total4 = (2 * NELEM) / 4;                 // float4 work items
    const int stride = gridDim.x * blockDim.x;
    for (int i = blockIdx.x * blockDim.x + threadIdx.x; i < total4; i += stride) {
        const int e = i * 4;                            // element index (multiple of 4)
        if (e < NELEM) {
            // ---- output 0: straight copy of y_initial ----
            const float4 v = *reinterpret_cast<const float4*>(y_initial + e);
            *reinterpret_cast<float4*>(out + e) = v;
        } else {
            // ---- output 1: nearest paste into bbox on zero canvas ----
            const int e2  = e - NELEM;
            const int b   = e2 >> 18;                   // / NPIX
            const int rem = e2 & (NPIX - 1);
            const int r   = rem >> 9;                   // / WW
            const int c0  = rem & (WW - 1);

            const int4 bb = *reinterpret_cast<const int4*>(bboxes + b * 4);
            const int x1 = bb.x, y1 = bb.y, x2 = bb.z, y2 = bb.w;

            float4 o = make_float4(0.f, 0.f, 0.f, 0.f);
            if (r >= y1 && r < y2) {
                const int h = y2 - y1;                  // in [128, 256]
                const int w = x2 - x1;                  // in [128, 256]
                // src_r: numerator >= 0 here, so C trunc == Python floor.
                int sr = ((r - y1) * HCC) / h;
                sr = min(max(sr, 0), HCC - 1);
                const float* src = y_cropped + ((long)b * HCC + sr) * WCC;
                float vals[4];
#pragma unroll
                for (int j = 0; j < 4; ++j) {
                    const int c = c0 + j;
                    if (c >= x1 && c < x2) {
                        int sc = ((c - x1) * WCC) / w;  // numerator >= 0
                        sc = min(max(sc, 0), WCC - 1);
                        vals[j] = src[sc];
                    } else {
                        vals[j] = 0.f;
                    }
                }
                o = make_float4(vals[0], vals[1], vals[2], vals[3]);
            }
            *reinterpret_cast<float4*>(out + e) = o;
        }
    }
}

extern "C" void kernel_launch(void* const* d_in, const int* in_sizes, int n_in,
                              void* d_out, int out_size, void* d_ws, size_t ws_size,
                              hipStream_t stream) {
    // Inputs (setup_inputs order): x [unused], y_initial, y_cropped, bboxes
    const float* y_initial = (const float*)d_in[1];
    const float* y_cropped = (const float*)d_in[2];
    const int*   bboxes    = (const int*)d_in[3];
    float*       out       = (float*)d_out;

    const int total4 = (2 * NELEM) / 4;       // 4,194,304 work items
    const int block  = 256;
    int grid = (total4 + block - 1) / block;  // 16384
    if (grid > 4096) grid = 4096;             // grid-stride, ~16 blocks/CU

    TransformedSegmentation_84971632984244_kernel<<<grid, block, 0, stream>>>(
        y_initial, y_cropped, bboxes, out);
}